// Round 8
// baseline (337.519 us; speedup 1.0000x reference)
//
#include <hip/hip_runtime.h>
#include <hip/hip_fp16.h>
#include <type_traits>

// GCN 2-layer forward: out = A( relu(A(X@W1)+b1) @ W2 ) + b2
// CSR build via 2-level LDS-staged binning. Intermediates fp16, pre-scaled by
// dis so aggregation = pure row-sum gather: out[v]=dv*(sum Hs[s]+Hs[v])+b.
// Agg: 4 node streams/wave (16 lanes each, 256B/row via one instruction),
// 8-edge batches, NO double-buffer (stay under the 64-VGPR occupancy cliff),
// tail edges masked by gathering a dummy all-zero row (index N).

constexpr int BSH = 9;              // 512 nodes per bucket
constexpr int BNODES = 1 << BSH;
constexpr int CHUNK = 4096;         // edges per scatter block
constexpr int CAP = 12288;          // place LDS staging capacity (mean ~8200)

__global__ __launch_bounds__(256) void zero_kernel(int* __restrict__ p, int n) {
    int i = blockIdx.x * 256 + threadIdx.x;
    if (i < n) p[i] = 0;
}

__global__ __launch_bounds__(256) void zero_halfs_kernel(__half* __restrict__ p, int n) {
    int i = threadIdx.x;
    if (i < n) reinterpret_cast<unsigned short*>(p)[i] = 0;
}

__global__ __launch_bounds__(256) void hist_kernel(const int* __restrict__ col,
                                                   int* __restrict__ bhist,
                                                   int E, int NB) {
    __shared__ int lh[256];
    int t = threadIdx.x;
    lh[t] = 0;
    __syncthreads();
    for (int i = blockIdx.x * 256 + t; i < E; i += gridDim.x * 256)
        atomicAdd(&lh[col[i] >> BSH], 1);
    __syncthreads();
    if (t < NB && lh[t]) atomicAdd(&bhist[t], lh[t]);
}

__global__ __launch_bounds__(256) void bbase_scan_kernel(const int* __restrict__ bhist,
                                                         int* __restrict__ bbase,
                                                         int* __restrict__ bcur, int NB) {
    __shared__ int s[256];
    int t = threadIdx.x;
    int v = (t < NB) ? bhist[t] : 0;
    s[t] = v;
    __syncthreads();
    for (int d = 1; d < 256; d <<= 1) {
        int u = (t >= d) ? s[t - d] : 0;
        __syncthreads();
        s[t] += u;
        __syncthreads();
    }
    if (t < NB) { bbase[t] = s[t] - v; bcur[t] = s[t] - v; }
    if (t == NB - 1) bbase[NB] = s[t];
}

__global__ __launch_bounds__(256) void bucket_scatter_kernel(const int* __restrict__ row,
                                                             const int* __restrict__ col,
                                                             int* __restrict__ bcur,
                                                             int2* __restrict__ pairs,
                                                             int E, int NB) {
    __shared__ int2 sp[CHUNK];
    __shared__ int lhist[256], lofs[256], lcur[256], gbase[256];
    int t = threadIdx.x;
    int start = blockIdx.x * CHUNK;
    int cnt = min(CHUNK, E - start);
    lhist[t] = 0;
    __syncthreads();
    for (int i = t; i < cnt; i += 256)
        atomicAdd(&lhist[col[start + i] >> BSH], 1);
    __syncthreads();
    int v = lhist[t];
    lofs[t] = v;
    __syncthreads();
    for (int d = 1; d < 256; d <<= 1) {
        int u = (t >= d) ? lofs[t - d] : 0;
        __syncthreads();
        lofs[t] += u;
        __syncthreads();
    }
    int excl = lofs[t] - v;
    lofs[t] = excl;
    lcur[t] = excl;
    if (t < NB && v > 0) gbase[t] = atomicAdd(&bcur[t], v);
    __syncthreads();
    for (int i = t; i < cnt; i += 256) {
        int c = col[start + i];
        int s = row[start + i];
        int lp = atomicAdd(&lcur[c >> BSH], 1);
        sp[lp] = make_int2(s, c);
    }
    __syncthreads();
    for (int i = t; i < cnt; i += 256) {
        int2 pr = sp[i];
        int b = pr.y >> BSH;
        pairs[gbase[b] + (i - lofs[b])] = pr;
    }
}

__global__ __launch_bounds__(256) void place_kernel(const int2* __restrict__ pairs,
                                                    const int* __restrict__ bbase,
                                                    int* __restrict__ off,
                                                    float* __restrict__ dis,
                                                    int* __restrict__ csr, int N, int NB) {
    __shared__ int lhist[BNODES], lexcl[BNODES], lcur2[BNODES];
    __shared__ int sscan[256];
    __shared__ int lout[CAP];
    int b = blockIdx.x;
    int t = threadIdx.x;
    int n0 = b << BSH;
    int n1 = min(n0 + BNODES, N);
    int nn = n1 - n0;
    int base = bbase[b];
    int cnt = bbase[b + 1] - base;
    lhist[2 * t] = 0;
    lhist[2 * t + 1] = 0;
    __syncthreads();
    for (int i = t; i < cnt; i += 256)
        atomicAdd(&lhist[pairs[base + i].y - n0], 1);
    __syncthreads();
    int a0 = lhist[2 * t], a1 = lhist[2 * t + 1];
    int ps = a0 + a1;
    sscan[t] = ps;
    __syncthreads();
    for (int d = 1; d < 256; d <<= 1) {
        int u = (t >= d) ? sscan[t - d] : 0;
        __syncthreads();
        sscan[t] += u;
        __syncthreads();
    }
    int pexcl = sscan[t] - ps;
    lexcl[2 * t] = pexcl;
    lexcl[2 * t + 1] = pexcl + a0;
    lcur2[2 * t] = pexcl;
    lcur2[2 * t + 1] = pexcl + a0;
    __syncthreads();
    for (int i = t; i < nn; i += 256) {
        off[n0 + i] = base + lexcl[i];
        dis[n0 + i] = rsqrtf((float)(lhist[i] + 1));   // +1 self loop
    }
    if (b == NB - 1 && t == 0) off[N] = base + cnt;
    for (int i = t; i < cnt; i += 256) {
        int2 pr = pairs[base + i];
        int lp = atomicAdd(&lcur2[pr.y - n0], 1);
        if (lp < CAP) lout[lp] = pr.x;
        else csr[base + lp] = pr.x;
    }
    __syncthreads();
    int staged = min(cnt, CAP);
    for (int i = t; i < staged; i += 256) csr[base + i] = lout[i];
}

// Y[M,TN] (fp16) = dis[row] * (X[M,128] @ W[128,TN]).  X: float | __half.
template<int TN, typename TI>
__global__ __launch_bounds__(256) void gemm_kernel(const TI* __restrict__ X,
                                                   const float* __restrict__ W,
                                                   const float* __restrict__ dis,
                                                   __half* __restrict__ Y, int M) {
    constexpr int K = 128, KC = 32, TM = 64;
    constexpr int CPT = TN / 16;
    __shared__ float As[KC][TM + 8];
    __shared__ float Bs[KC][TN];
    int tid = threadIdx.x;
    int row0 = blockIdx.x * TM;
    int tx = tid & 15, ty = tid >> 4;
    float acc[4][CPT];
#pragma unroll
    for (int i = 0; i < 4; ++i)
#pragma unroll
        for (int j = 0; j < CPT; ++j) acc[i][j] = 0.0f;

    for (int k0 = 0; k0 < K; k0 += KC) {
        if constexpr (std::is_same<TI, float>::value) {
#pragma unroll
            for (int j = 0; j < 2; ++j) {
                int l = tid + 256 * j;               // 0..511
                int r = l >> 3;
                int kq = l & 7;
                int row = row0 + r;
                float4 v = make_float4(0.f, 0.f, 0.f, 0.f);
                if (row < M) v = *(const float4*)(X + (size_t)row * K + k0 + kq * 4);
                As[kq * 4 + 0][r] = v.x;
                As[kq * 4 + 1][r] = v.y;
                As[kq * 4 + 2][r] = v.z;
                As[kq * 4 + 3][r] = v.w;
            }
        } else {
            int r = tid >> 2;                        // 0..63
            int kq = tid & 3;                        // 4 x 8 halfs = 32 k
            int row = row0 + r;
            uint4 u = make_uint4(0, 0, 0, 0);
            if (row < M) u = *(const uint4*)(X + (size_t)row * K + k0 + kq * 8);
            const unsigned int uu[4] = {u.x, u.y, u.z, u.w};
#pragma unroll
            for (int q = 0; q < 4; ++q) {
                __half2 hv = *reinterpret_cast<const __half2*>(&uu[q]);
                float2 f = __half22float2(hv);
                As[kq * 8 + 2 * q + 0][r] = f.x;
                As[kq * 8 + 2 * q + 1][r] = f.y;
            }
        }
#pragma unroll
        for (int j = 0; j < KC * TN / 1024; ++j) {
            int l = tid + 256 * j;
            int kk = l / (TN / 4);
            int cq = l % (TN / 4);
            *(float4*)&Bs[kk][cq * 4] = *(const float4*)(W + (size_t)(k0 + kk) * TN + cq * 4);
        }
        __syncthreads();
#pragma unroll
        for (int kk = 0; kk < KC; ++kk) {
            float4 av = *(const float4*)&As[kk][ty * 4];
            float a[4] = {av.x, av.y, av.z, av.w};
            float b[CPT];
#pragma unroll
            for (int q = 0; q < CPT / 4; ++q) {
                float4 bv = *(const float4*)&Bs[kk][tx * CPT + q * 4];
                b[q * 4 + 0] = bv.x; b[q * 4 + 1] = bv.y;
                b[q * 4 + 2] = bv.z; b[q * 4 + 3] = bv.w;
            }
#pragma unroll
            for (int i = 0; i < 4; ++i)
#pragma unroll
                for (int j = 0; j < CPT; ++j) acc[i][j] = fmaf(a[i], b[j], acc[i][j]);
        }
        __syncthreads();
    }
#pragma unroll
    for (int i = 0; i < 4; ++i) {
        int row = row0 + ty * 4 + i;
        if (row < M) {
            float sc = dis[row];
            __half2 hv[CPT / 2];
#pragma unroll
            for (int q = 0; q < CPT / 2; ++q)
                hv[q] = __float22half2_rn(make_float2(sc * acc[i][2 * q],
                                                      sc * acc[i][2 * q + 1]));
            *(uint2*)(Y + (size_t)row * TN + tx * CPT) = *reinterpret_cast<uint2*>(&hv[0]);
            if constexpr (CPT == 8)
                *(uint2*)(Y + (size_t)row * TN + tx * CPT + 4) =
                    *reinterpret_cast<uint2*>(&hv[2]);
        }
    }
}

// out[v] = dv*( sum_{e} Hs[src] + Hs[v] ) + b  (Hs pre-scaled by dis), opt relu.
// 16 lanes/node (4 streams/wave); 8-edge batches; tail gathers dummy zero
// row N. Single batch buffer live (32 dest VGPR) + launch_bounds pins 8 w/EU.
template<int C, bool RELU, typename TOUT>
__global__ __launch_bounds__(256, 8) void agg_kernel(const __half* __restrict__ Hs,
                                                     const int* __restrict__ off,
                                                     const int* __restrict__ src,
                                                     const float* __restrict__ dis,
                                                     const float* __restrict__ bias,
                                                     TOUT* __restrict__ out, int N) {
    constexpr int HPL = C / 16;                  // halfs per lane: 8 or 4
    constexpr int NV = HPL / 2;                  // u32 words per row-slice
    using VT = std::conditional_t<HPL == 8, uint4, uint2>;
    int node = blockIdx.x * 16 + (threadIdx.x >> 4);
    if (node >= N) return;
    int lane = threadIdx.x & 15;
    float dv = dis[node];
    float acc[HPL];
    {   // self term
        VT sv = *(const VT*)(Hs + (size_t)node * C + lane * HPL);
        const unsigned int* u = reinterpret_cast<const unsigned int*>(&sv);
#pragma unroll
        for (int q = 0; q < NV; ++q) {
            float2 f = __half22float2(*reinterpret_cast<const __half2*>(&u[q]));
            acc[2 * q] = f.x;
            acc[2 * q + 1] = f.y;
        }
    }
    int e0 = off[node], e1 = off[node + 1];
    for (int e = e0; e < e1; e += 8) {
        int s[8];
#pragma unroll
        for (int k = 0; k < 8; ++k) {
            int idx = e + k;
            s[k] = (idx < e1) ? src[idx] : N;    // row N is all zeros
        }
        VT v[8];
#pragma unroll
        for (int k = 0; k < 8; ++k)
            v[k] = *(const VT*)(Hs + (size_t)s[k] * C + lane * HPL);
#pragma unroll
        for (int k = 0; k < 8; ++k) {
            const unsigned int* u = reinterpret_cast<const unsigned int*>(&v[k]);
#pragma unroll
            for (int q = 0; q < NV; ++q) {
                float2 f = __half22float2(*reinterpret_cast<const __half2*>(&u[q]));
                acc[2 * q] += f.x;
                acc[2 * q + 1] += f.y;
            }
        }
    }
    float r[HPL];
#pragma unroll
    for (int f = 0; f < HPL; ++f) {
        r[f] = fmaf(dv, acc[f], bias[lane * HPL + f]);
        if (RELU) r[f] = fmaxf(r[f], 0.0f);
    }
    if constexpr (std::is_same<TOUT, __half>::value) {
        __half2 hv[NV];
#pragma unroll
        for (int q = 0; q < NV; ++q)
            hv[q] = __float22half2_rn(make_float2(r[2 * q], r[2 * q + 1]));
        *(VT*)(out + (size_t)node * C + lane * HPL) = *reinterpret_cast<VT*>(&hv[0]);
    } else {
        if constexpr (HPL == 8) {
            *(float4*)(out + (size_t)node * C + lane * 8) =
                make_float4(r[0], r[1], r[2], r[3]);
            *(float4*)(out + (size_t)node * C + lane * 8 + 4) =
                make_float4(r[4], r[5], r[6], r[7]);
        } else {
            *(float4*)(out + (size_t)node * C + lane * 4) =
                make_float4(r[0], r[1], r[2], r[3]);
        }
    }
}

extern "C" void kernel_launch(void* const* d_in, const int* in_sizes, int n_in,
                              void* d_out, int out_size, void* d_ws, size_t ws_size,
                              hipStream_t stream) {
    const float* x  = (const float*)d_in[0];
    const int*   ei = (const int*)d_in[1];
    const float* W1 = (const float*)d_in[2];
    const float* b1 = (const float*)d_in[3];
    const float* W2 = (const float*)d_in[4];
    const float* b2 = (const float*)d_in[5];
    float* out = (float*)d_out;

    int N = in_sizes[0] / 128;
    int E = in_sizes[1] / 2;
    const int* row = ei;        // edge_index[0] = sources
    const int* col = ei + E;    // edge_index[1] = targets
    int NB = (N + BNODES - 1) >> BSH;

    char* ws = (char*)d_ws;
    size_t o = 0;
    auto alloc = [&](size_t bytes) -> void* {
        void* p = ws + o;
        o = (o + bytes + 255) & ~(size_t)255;
        return p;
    };
    int*    bhist = (int*)alloc((size_t)(NB + 1) * 4);
    int*    bbase = (int*)alloc((size_t)(NB + 1) * 4);
    int*    bcur  = (int*)alloc((size_t)NB * 4);
    int*    off   = (int*)alloc((size_t)(N + 1) * 4);
    float*  dis   = (float*)alloc((size_t)N * 4);
    int*    csr   = (int*)alloc((size_t)E * 4);
    __half* xw    = (__half*)alloc(((size_t)N * 128 + 128) * 2); // +dummy row N
    __half* h     = (__half*)alloc((size_t)N * 128 * 2);
    int2*   pairs = (int2*)alloc((size_t)E * 8);                 // dead after place
    __half* hw2   = xw;          // alias: dis*(h@W2), 64 cols fp16 (+dummy row N)

    zero_kernel<<<1, 256, 0, stream>>>(bhist, NB);
    zero_halfs_kernel<<<1, 256, 0, stream>>>(xw + (size_t)N * 128, 128);  // agg1 dummy
    hist_kernel<<<1024, 256, 0, stream>>>(col, bhist, E, NB);
    bbase_scan_kernel<<<1, 256, 0, stream>>>(bhist, bbase, bcur, NB);
    bucket_scatter_kernel<<<(E + CHUNK - 1) / CHUNK, 256, 0, stream>>>(row, col, bcur,
                                                                       pairs, E, NB);
    place_kernel<<<NB, 256, 0, stream>>>(pairs, bbase, off, dis, csr, N, NB);

    gemm_kernel<128, float><<<(N + 63) / 64, 256, 0, stream>>>(x, W1, dis, xw, N);
    agg_kernel<128, true, __half><<<(N + 15) / 16, 256, 0, stream>>>(xw, off, csr, dis,
                                                                     b1, h, N);
    gemm_kernel<64, __half><<<(N + 63) / 64, 256, 0, stream>>>(h, W2, dis, hw2, N);
    zero_halfs_kernel<<<1, 256, 0, stream>>>(hw2 + (size_t)N * 64, 64);   // agg2 dummy
    agg_kernel<64, false, float><<<(N + 15) / 16, 256, 0, stream>>>(hw2, off, csr, dis,
                                                                    b2, out, N);
}

// Round 9
// 205.271 us; speedup vs baseline: 1.6443x; 1.6443x over previous
//
#include <hip/hip_runtime.h>
#include <hip/hip_fp16.h>
#include <type_traits>

// GCN 2-layer forward: out = A( relu(A(X@W1)+b1) @ W2 ) + b2
// CSR build via 2-level LDS-staged binning. Intermediates fp16, pre-scaled by
// dis so aggregation = pure row-sum gather: out[v]=dv*(sum Hs[s]+Hs[v])+b.
// GEMMs use MFMA v_mfma_f32_16x16x32_f16 (W pre-transposed to fp16).
// Agg: round-6 config (2 nodes/wave, 32 lanes/node, 8-edge masked batches,
// VGPR 32, no launch_bounds cap — occupancy 8 waves/EU naturally).

constexpr int BSH = 9;              // 512 nodes per bucket
constexpr int BNODES = 1 << BSH;
constexpr int CHUNK = 4096;         // edges per scatter block
constexpr int CAP = 12288;          // place LDS staging capacity (mean ~8200)

typedef __attribute__((ext_vector_type(8))) _Float16 half8;
typedef __attribute__((ext_vector_type(4))) float f32x4;

__global__ __launch_bounds__(256) void zero_kernel(int* __restrict__ p, int n) {
    int i = blockIdx.x * 256 + threadIdx.x;
    if (i < n) p[i] = 0;
}

__global__ __launch_bounds__(256) void hist_kernel(const int* __restrict__ col,
                                                   int* __restrict__ bhist,
                                                   int E, int NB) {
    __shared__ int lh[256];
    int t = threadIdx.x;
    lh[t] = 0;
    __syncthreads();
    for (int i = blockIdx.x * 256 + t; i < E; i += gridDim.x * 256)
        atomicAdd(&lh[col[i] >> BSH], 1);
    __syncthreads();
    if (t < NB && lh[t]) atomicAdd(&bhist[t], lh[t]);
}

__global__ __launch_bounds__(256) void bbase_scan_kernel(const int* __restrict__ bhist,
                                                         int* __restrict__ bbase,
                                                         int* __restrict__ bcur, int NB) {
    __shared__ int s[256];
    int t = threadIdx.x;
    int v = (t < NB) ? bhist[t] : 0;
    s[t] = v;
    __syncthreads();
    for (int d = 1; d < 256; d <<= 1) {
        int u = (t >= d) ? s[t - d] : 0;
        __syncthreads();
        s[t] += u;
        __syncthreads();
    }
    if (t < NB) { bbase[t] = s[t] - v; bcur[t] = s[t] - v; }
    if (t == NB - 1) bbase[NB] = s[t];
}

__global__ __launch_bounds__(256) void bucket_scatter_kernel(const int* __restrict__ row,
                                                             const int* __restrict__ col,
                                                             int* __restrict__ bcur,
                                                             int2* __restrict__ pairs,
                                                             int E, int NB) {
    __shared__ int2 sp[CHUNK];
    __shared__ int lhist[256], lofs[256], lcur[256], gbase[256];
    int t = threadIdx.x;
    int start = blockIdx.x * CHUNK;
    int cnt = min(CHUNK, E - start);
    lhist[t] = 0;
    __syncthreads();
    for (int i = t; i < cnt; i += 256)
        atomicAdd(&lhist[col[start + i] >> BSH], 1);
    __syncthreads();
    int v = lhist[t];
    lofs[t] = v;
    __syncthreads();
    for (int d = 1; d < 256; d <<= 1) {
        int u = (t >= d) ? lofs[t - d] : 0;
        __syncthreads();
        lofs[t] += u;
        __syncthreads();
    }
    int excl = lofs[t] - v;
    lofs[t] = excl;
    lcur[t] = excl;
    if (t < NB && v > 0) gbase[t] = atomicAdd(&bcur[t], v);
    __syncthreads();
    for (int i = t; i < cnt; i += 256) {
        int c = col[start + i];
        int s = row[start + i];
        int lp = atomicAdd(&lcur[c >> BSH], 1);
        sp[lp] = make_int2(s, c);
    }
    __syncthreads();
    for (int i = t; i < cnt; i += 256) {
        int2 pr = sp[i];
        int b = pr.y >> BSH;
        pairs[gbase[b] + (i - lofs[b])] = pr;
    }
}

__global__ __launch_bounds__(256) void place_kernel(const int2* __restrict__ pairs,
                                                    const int* __restrict__ bbase,
                                                    int* __restrict__ off,
                                                    float* __restrict__ dis,
                                                    int* __restrict__ csr, int N, int NB) {
    __shared__ int lhist[BNODES], lexcl[BNODES], lcur2[BNODES];
    __shared__ int sscan[256];
    __shared__ int lout[CAP];
    int b = blockIdx.x;
    int t = threadIdx.x;
    int n0 = b << BSH;
    int n1 = min(n0 + BNODES, N);
    int nn = n1 - n0;
    int base = bbase[b];
    int cnt = bbase[b + 1] - base;
    lhist[2 * t] = 0;
    lhist[2 * t + 1] = 0;
    __syncthreads();
    for (int i = t; i < cnt; i += 256)
        atomicAdd(&lhist[pairs[base + i].y - n0], 1);
    __syncthreads();
    int a0 = lhist[2 * t], a1 = lhist[2 * t + 1];
    int ps = a0 + a1;
    sscan[t] = ps;
    __syncthreads();
    for (int d = 1; d < 256; d <<= 1) {
        int u = (t >= d) ? sscan[t - d] : 0;
        __syncthreads();
        sscan[t] += u;
        __syncthreads();
    }
    int pexcl = sscan[t] - ps;
    lexcl[2 * t] = pexcl;
    lexcl[2 * t + 1] = pexcl + a0;
    lcur2[2 * t] = pexcl;
    lcur2[2 * t + 1] = pexcl + a0;
    __syncthreads();
    for (int i = t; i < nn; i += 256) {
        off[n0 + i] = base + lexcl[i];
        dis[n0 + i] = rsqrtf((float)(lhist[i] + 1));   // +1 self loop
    }
    if (b == NB - 1 && t == 0) off[N] = base + cnt;
    for (int i = t; i < cnt; i += 256) {
        int2 pr = pairs[base + i];
        int lp = atomicAdd(&lcur2[pr.y - n0], 1);
        if (lp < CAP) lout[lp] = pr.x;
        else csr[base + lp] = pr.x;
    }
    __syncthreads();
    int staged = min(cnt, CAP);
    for (int i = t; i < staged; i += 256) csr[base + i] = lout[i];
}

// WT[n][k] (fp16) = W[k][n] (fp32). Coalesced read, tiny one-time transpose.
template<int TN>
__global__ __launch_bounds__(256) void wtrans_kernel(const float* __restrict__ W,
                                                     _Float16* __restrict__ WT) {
    int i = blockIdx.x * 256 + threadIdx.x;
    if (i < TN * 128) {
        int n = i % TN, k = i / TN;
        WT[n * 128 + k] = (_Float16)W[k * TN + n];
    }
}

// Y[M,TN] (fp16) = dis[row] * (X[M,128] @ W).  WT is W transposed [TN][128]
// fp16.  MFMA 16x16x32_f16: block = 4 waves, 64 rows; wave w -> rows w*16..+16.
// A/B frag: lane l -> row/col l&15, k = (l>>4)*8+j.  C/D: col=l&15,
// row=(l>>4)*4+reg (m89-verified layout).
template<int TN, typename TI>
__global__ __launch_bounds__(256) void gemm_kernel(const TI* __restrict__ X,
                                                   const _Float16* __restrict__ WT,
                                                   const float* __restrict__ dis,
                                                   __half* __restrict__ Y, int M) {
    constexpr int K = 128;
    constexpr int NT = TN / 16;
    constexpr int LDA = 136;                 // pad: 272B rows -> <=2-way LDS conflict
    __shared__ _Float16 Ah[64 * LDA];
    __shared__ _Float16 Bh[TN * LDA];
    int tid = threadIdx.x;
    int row0 = blockIdx.x * 64;

    // stage B: all of WT (TN x 128 fp16), coalesced uint4
#pragma unroll
    for (int j = 0; j < TN / 16; ++j) {      // TN*128/8 loads / 256 threads
        int lin = tid + j * 256;
        int n = lin >> 4, kq = lin & 15;
        *(uint4*)&Bh[n * LDA + kq * 8] = *(const uint4*)(WT + n * 128 + kq * 8);
    }
    // stage A: 64 rows x 128, convert to fp16 if needed
    if constexpr (std::is_same<TI, float>::value) {
#pragma unroll
        for (int j = 0; j < 8; ++j) {
            int lin = tid + j * 256;         // 64 rows * 32 float4-groups
            int r = lin >> 5, kq = lin & 31;
            int row = row0 + r;
            float4 v = make_float4(0.f, 0.f, 0.f, 0.f);
            if (row < M) v = *(const float4*)(X + (size_t)row * K + kq * 4);
            __half2 h01 = __float22half2_rn(make_float2(v.x, v.y));
            __half2 h23 = __float22half2_rn(make_float2(v.z, v.w));
            uint2 u = make_uint2(*reinterpret_cast<unsigned*>(&h01),
                                 *reinterpret_cast<unsigned*>(&h23));
            *(uint2*)&Ah[r * LDA + kq * 4] = u;
        }
    } else {
#pragma unroll
        for (int j = 0; j < 4; ++j) {
            int lin = tid + j * 256;         // 64 rows * 16 uint4-groups
            int r = lin >> 4, kq = lin & 15;
            int row = row0 + r;
            uint4 u = make_uint4(0, 0, 0, 0);
            if (row < M) u = *(const uint4*)(X + (size_t)row * K + kq * 8);
            *(uint4*)&Ah[r * LDA + kq * 8] = u;
        }
    }
    __syncthreads();

    int w = tid >> 6, l = tid & 63;
    int lr = l & 15, kg = l >> 4;
    f32x4 acc[NT];
#pragma unroll
    for (int nt = 0; nt < NT; ++nt) acc[nt] = (f32x4){0.f, 0.f, 0.f, 0.f};

    const _Float16* arow = &Ah[(w * 16 + lr) * LDA + kg * 8];
#pragma unroll
    for (int ks = 0; ks < 4; ++ks) {
        half8 af = *(const half8*)(arow + ks * 32);
#pragma unroll
        for (int nt = 0; nt < NT; ++nt) {
            half8 bf = *(const half8*)(&Bh[(nt * 16 + lr) * LDA + ks * 32 + kg * 8]);
            acc[nt] = __builtin_amdgcn_mfma_f32_16x16x32_f16(af, bf, acc[nt], 0, 0, 0);
        }
    }

#pragma unroll
    for (int j = 0; j < 4; ++j) {
        int grow = row0 + w * 16 + kg * 4 + j;
        if (grow < M) {
            float sc = dis[grow];
#pragma unroll
            for (int nt = 0; nt < NT; ++nt)
                Y[(size_t)grow * TN + nt * 16 + lr] = __float2half_rn(sc * acc[nt][j]);
        }
    }
}

// out[v] = dv*( sum_{e} Hs[src] + Hs[v] ) + b  (Hs pre-scaled by dis), opt relu.
// Round-6 config: 2 nodes per wave (32 lanes each); 8 edges in flight; masked
// tail (clamped index, weight 0/1).  VGPR 32 -> 8 waves/EU naturally.
template<int C, bool RELU, typename TOUT>
__global__ __launch_bounds__(256) void agg_kernel(const __half* __restrict__ Hs,
                                                  const int* __restrict__ off,
                                                  const int* __restrict__ src,
                                                  const float* __restrict__ dis,
                                                  const float* __restrict__ bias,
                                                  TOUT* __restrict__ out, int N) {
    constexpr int HPL = C / 32;                  // halfs per lane: 4 or 2
    int node = blockIdx.x * 8 + (threadIdx.x >> 5);
    if (node >= N) return;
    int lane = threadIdx.x & 31;
    float dv = dis[node];
    float acc[HPL];
    {   // self term (Hs[v] = dis[v]*row)
        const __half* hp = Hs + (size_t)node * C + lane * HPL;
        if constexpr (HPL == 4) {
            uint2 u = *(const uint2*)hp;
            float2 f0 = __half22float2(*reinterpret_cast<__half2*>(&u.x));
            float2 f1 = __half22float2(*reinterpret_cast<__half2*>(&u.y));
            acc[0] = f0.x; acc[1] = f0.y; acc[2] = f1.x; acc[3] = f1.y;
        } else {
            float2 f0 = __half22float2(*(const __half2*)hp);
            acc[0] = f0.x; acc[1] = f0.y;
        }
    }
    int e0 = off[node], e1 = off[node + 1];
    for (int e = e0; e < e1; e += 8) {
        int s[8];
        float w[8];
#pragma unroll
        for (int k = 0; k < 8; ++k) {
            int idx = e + k;
            bool ok = idx < e1;
            s[k] = src[ok ? idx : e1 - 1];
            w[k] = ok ? 1.0f : 0.0f;
        }
        if constexpr (HPL == 4) {
            uint2 v[8];
#pragma unroll
            for (int k = 0; k < 8; ++k)
                v[k] = *(const uint2*)(Hs + (size_t)s[k] * C + lane * 4);
#pragma unroll
            for (int k = 0; k < 8; ++k) {
                float2 f0 = __half22float2(*reinterpret_cast<__half2*>(&v[k].x));
                float2 f1 = __half22float2(*reinterpret_cast<__half2*>(&v[k].y));
                acc[0] = fmaf(w[k], f0.x, acc[0]);
                acc[1] = fmaf(w[k], f0.y, acc[1]);
                acc[2] = fmaf(w[k], f1.x, acc[2]);
                acc[3] = fmaf(w[k], f1.y, acc[3]);
            }
        } else {
            unsigned int v[8];
#pragma unroll
            for (int k = 0; k < 8; ++k)
                v[k] = *(const unsigned int*)(Hs + (size_t)s[k] * C + lane * 2);
#pragma unroll
            for (int k = 0; k < 8; ++k) {
                float2 f0 = __half22float2(*reinterpret_cast<__half2*>(&v[k]));
                acc[0] = fmaf(w[k], f0.x, acc[0]);
                acc[1] = fmaf(w[k], f0.y, acc[1]);
            }
        }
    }
    float r[HPL];
#pragma unroll
    for (int f = 0; f < HPL; ++f) {
        r[f] = fmaf(dv, acc[f], bias[lane * HPL + f]);
        if (RELU) r[f] = fmaxf(r[f], 0.0f);
    }
    if constexpr (std::is_same<TOUT, __half>::value) {
        __half2 hv[HPL / 2];
#pragma unroll
        for (int q = 0; q < HPL / 2; ++q)
            hv[q] = __float22half2_rn(make_float2(r[2 * q], r[2 * q + 1]));
        if constexpr (HPL == 4)
            *(uint2*)(out + (size_t)node * C + lane * 4) = *reinterpret_cast<uint2*>(&hv[0]);
        else
            *(unsigned int*)(out + (size_t)node * C + lane * 2) =
                *reinterpret_cast<unsigned int*>(&hv[0]);
    } else {
        if constexpr (HPL == 4) {
            *(float4*)(out + (size_t)node * C + lane * 4) =
                make_float4(r[0], r[1], r[2], r[3]);
        } else {
            *(float2*)(out + (size_t)node * C + lane * 2) = make_float2(r[0], r[1]);
        }
    }
}

extern "C" void kernel_launch(void* const* d_in, const int* in_sizes, int n_in,
                              void* d_out, int out_size, void* d_ws, size_t ws_size,
                              hipStream_t stream) {
    const float* x  = (const float*)d_in[0];
    const int*   ei = (const int*)d_in[1];
    const float* W1 = (const float*)d_in[2];
    const float* b1 = (const float*)d_in[3];
    const float* W2 = (const float*)d_in[4];
    const float* b2 = (const float*)d_in[5];
    float* out = (float*)d_out;

    int N = in_sizes[0] / 128;
    int E = in_sizes[1] / 2;
    const int* row = ei;        // edge_index[0] = sources
    const int* col = ei + E;    // edge_index[1] = targets
    int NB = (N + BNODES - 1) >> BSH;

    char* ws = (char*)d_ws;
    size_t o = 0;
    auto alloc = [&](size_t bytes) -> void* {
        void* p = ws + o;
        o = (o + bytes + 255) & ~(size_t)255;
        return p;
    };
    int*      bhist = (int*)alloc((size_t)(NB + 1) * 4);
    int*      bbase = (int*)alloc((size_t)(NB + 1) * 4);
    int*      bcur  = (int*)alloc((size_t)NB * 4);
    int*      off   = (int*)alloc((size_t)(N + 1) * 4);
    float*    dis   = (float*)alloc((size_t)N * 4);
    int*      csr   = (int*)alloc((size_t)E * 4);
    _Float16* w1t   = (_Float16*)alloc(128 * 128 * 2);
    _Float16* w2t   = (_Float16*)alloc(64 * 128 * 2);
    __half*   xw    = (__half*)alloc((size_t)N * 128 * 2);   // dis*(X@W1)
    __half*   h     = (__half*)alloc((size_t)N * 128 * 2);   // relu activations
    int2*     pairs = (int2*)alloc((size_t)E * 8);           // dead after place
    __half*   hw2   = xw;        // alias: dis*(h@W2), 64 cols fp16

    zero_kernel<<<1, 256, 0, stream>>>(bhist, NB);
    wtrans_kernel<128><<<64, 256, 0, stream>>>(W1, w1t);
    wtrans_kernel<64><<<32, 256, 0, stream>>>(W2, w2t);
    hist_kernel<<<1024, 256, 0, stream>>>(col, bhist, E, NB);
    bbase_scan_kernel<<<1, 256, 0, stream>>>(bhist, bbase, bcur, NB);
    bucket_scatter_kernel<<<(E + CHUNK - 1) / CHUNK, 256, 0, stream>>>(row, col, bcur,
                                                                       pairs, E, NB);
    place_kernel<<<NB, 256, 0, stream>>>(pairs, bbase, off, dis, csr, N, NB);

    gemm_kernel<128, float><<<(N + 63) / 64, 256, 0, stream>>>(x, w1t, dis, xw, N);
    agg_kernel<128, true, __half><<<(N + 7) / 8, 256, 0, stream>>>(xw, off, csr, dis,
                                                                   b1, h, N);
    gemm_kernel<64, __half><<<(N + 63) / 64, 256, 0, stream>>>(h, w2t, dis, hw2, N);
    agg_kernel<64, false, float><<<(N + 7) / 8, 256, 0, stream>>>(hw2, off, csr, dis,
                                                                  b2, out, N);
}

// Round 10
// 204.333 us; speedup vs baseline: 1.6518x; 1.0046x over previous
//
#include <hip/hip_runtime.h>
#include <hip/hip_fp16.h>
#include <type_traits>

// GCN 2-layer forward: out = A( relu(A(X@W1)+b1) @ W2 ) + b2
// CSR build via 2-level LDS-staged binning. Intermediates fp16, pre-scaled by
// dis so aggregation = pure row-sum gather: out[v]=dv*(sum Hs[s]+Hs[v])+b.
// GEMMs: MFMA v_mfma_f32_16x16x32_f16 (W pre-transposed fp16).
// Agg: 16 lanes/node (4 streams/wave, one 512B gather instr = 4 edges),
// single 8-batch buffer (~56 VGPR, under the 64 cliff), NO launch_bounds cap
// (R8 lesson: cap->scratch spill), tail masked via dummy zero row N.

constexpr int BSH = 9;              // 512 nodes per bucket
constexpr int BNODES = 1 << BSH;
constexpr int CHUNK = 4096;         // edges per scatter block
constexpr int CAP = 12288;          // place LDS staging capacity (mean ~8200)

typedef __attribute__((ext_vector_type(8))) _Float16 half8;
typedef __attribute__((ext_vector_type(4))) float f32x4;

__global__ __launch_bounds__(256) void zero_kernel(int* __restrict__ p, int n) {
    int i = blockIdx.x * 256 + threadIdx.x;
    if (i < n) p[i] = 0;
}

__global__ __launch_bounds__(256) void zero_halfs_kernel(__half* __restrict__ p, int n) {
    int i = threadIdx.x;
    if (i < n) reinterpret_cast<unsigned short*>(p)[i] = 0;
}

__global__ __launch_bounds__(256) void hist_kernel(const int* __restrict__ col,
                                                   int* __restrict__ bhist,
                                                   int E, int NB) {
    __shared__ int lh[256];
    int t = threadIdx.x;
    lh[t] = 0;
    __syncthreads();
    for (int i = blockIdx.x * 256 + t; i < E; i += gridDim.x * 256)
        atomicAdd(&lh[col[i] >> BSH], 1);
    __syncthreads();
    if (t < NB && lh[t]) atomicAdd(&bhist[t], lh[t]);
}

__global__ __launch_bounds__(256) void bbase_scan_kernel(const int* __restrict__ bhist,
                                                         int* __restrict__ bbase,
                                                         int* __restrict__ bcur, int NB) {
    __shared__ int s[256];
    int t = threadIdx.x;
    int v = (t < NB) ? bhist[t] : 0;
    s[t] = v;
    __syncthreads();
    for (int d = 1; d < 256; d <<= 1) {
        int u = (t >= d) ? s[t - d] : 0;
        __syncthreads();
        s[t] += u;
        __syncthreads();
    }
    if (t < NB) { bbase[t] = s[t] - v; bcur[t] = s[t] - v; }
    if (t == NB - 1) bbase[NB] = s[t];
}

__global__ __launch_bounds__(256) void bucket_scatter_kernel(const int* __restrict__ row,
                                                             const int* __restrict__ col,
                                                             int* __restrict__ bcur,
                                                             int2* __restrict__ pairs,
                                                             int E, int NB) {
    __shared__ int2 sp[CHUNK];
    __shared__ int lhist[256], lofs[256], lcur[256], gbase[256];
    int t = threadIdx.x;
    int start = blockIdx.x * CHUNK;
    int cnt = min(CHUNK, E - start);
    lhist[t] = 0;
    __syncthreads();
    for (int i = t; i < cnt; i += 256)
        atomicAdd(&lhist[col[start + i] >> BSH], 1);
    __syncthreads();
    int v = lhist[t];
    lofs[t] = v;
    __syncthreads();
    for (int d = 1; d < 256; d <<= 1) {
        int u = (t >= d) ? lofs[t - d] : 0;
        __syncthreads();
        lofs[t] += u;
        __syncthreads();
    }
    int excl = lofs[t] - v;
    lofs[t] = excl;
    lcur[t] = excl;
    if (t < NB && v > 0) gbase[t] = atomicAdd(&bcur[t], v);
    __syncthreads();
    for (int i = t; i < cnt; i += 256) {
        int c = col[start + i];
        int s = row[start + i];
        int lp = atomicAdd(&lcur[c >> BSH], 1);
        sp[lp] = make_int2(s, c);
    }
    __syncthreads();
    for (int i = t; i < cnt; i += 256) {
        int2 pr = sp[i];
        int b = pr.y >> BSH;
        pairs[gbase[b] + (i - lofs[b])] = pr;
    }
}

__global__ __launch_bounds__(256) void place_kernel(const int2* __restrict__ pairs,
                                                    const int* __restrict__ bbase,
                                                    int* __restrict__ off,
                                                    float* __restrict__ dis,
                                                    int* __restrict__ csr, int N, int NB) {
    __shared__ int lhist[BNODES], lexcl[BNODES], lcur2[BNODES];
    __shared__ int sscan[256];
    __shared__ int lout[CAP];
    int b = blockIdx.x;
    int t = threadIdx.x;
    int n0 = b << BSH;
    int n1 = min(n0 + BNODES, N);
    int nn = n1 - n0;
    int base = bbase[b];
    int cnt = bbase[b + 1] - base;
    lhist[2 * t] = 0;
    lhist[2 * t + 1] = 0;
    __syncthreads();
    for (int i = t; i < cnt; i += 256)
        atomicAdd(&lhist[pairs[base + i].y - n0], 1);
    __syncthreads();
    int a0 = lhist[2 * t], a1 = lhist[2 * t + 1];
    int ps = a0 + a1;
    sscan[t] = ps;
    __syncthreads();
    for (int d = 1; d < 256; d <<= 1) {
        int u = (t >= d) ? sscan[t - d] : 0;
        __syncthreads();
        sscan[t] += u;
        __syncthreads();
    }
    int pexcl = sscan[t] - ps;
    lexcl[2 * t] = pexcl;
    lexcl[2 * t + 1] = pexcl + a0;
    lcur2[2 * t] = pexcl;
    lcur2[2 * t + 1] = pexcl + a0;
    __syncthreads();
    for (int i = t; i < nn; i += 256) {
        off[n0 + i] = base + lexcl[i];
        dis[n0 + i] = rsqrtf((float)(lhist[i] + 1));   // +1 self loop
    }
    if (b == NB - 1 && t == 0) off[N] = base + cnt;
    for (int i = t; i < cnt; i += 256) {
        int2 pr = pairs[base + i];
        int lp = atomicAdd(&lcur2[pr.y - n0], 1);
        if (lp < CAP) lout[lp] = pr.x;
        else csr[base + lp] = pr.x;
    }
    __syncthreads();
    int staged = min(cnt, CAP);
    for (int i = t; i < staged; i += 256) csr[base + i] = lout[i];
}

// WT[n][k] (fp16) = W[k][n] (fp32).
template<int TN>
__global__ __launch_bounds__(256) void wtrans_kernel(const float* __restrict__ W,
                                                     _Float16* __restrict__ WT) {
    int i = blockIdx.x * 256 + threadIdx.x;
    if (i < TN * 128) {
        int n = i % TN, k = i / TN;
        WT[n * 128 + k] = (_Float16)W[k * TN + n];
    }
}

// Y[M,TN] (fp16) = dis[row] * (X[M,128] @ W).  MFMA 16x16x32_f16.
template<int TN, typename TI>
__global__ __launch_bounds__(256) void gemm_kernel(const TI* __restrict__ X,
                                                   const _Float16* __restrict__ WT,
                                                   const float* __restrict__ dis,
                                                   __half* __restrict__ Y, int M) {
    constexpr int K = 128;
    constexpr int NT = TN / 16;
    constexpr int LDA = 136;                 // pad: <=2-way LDS conflict (free)
    __shared__ _Float16 Ah[64 * LDA];
    __shared__ _Float16 Bh[TN * LDA];
    int tid = threadIdx.x;
    int row0 = blockIdx.x * 64;

#pragma unroll
    for (int j = 0; j < TN / 16; ++j) {
        int lin = tid + j * 256;
        int n = lin >> 4, kq = lin & 15;
        *(uint4*)&Bh[n * LDA + kq * 8] = *(const uint4*)(WT + n * 128 + kq * 8);
    }
    if constexpr (std::is_same<TI, float>::value) {
#pragma unroll
        for (int j = 0; j < 8; ++j) {
            int lin = tid + j * 256;
            int r = lin >> 5, kq = lin & 31;
            int row = row0 + r;
            float4 v = make_float4(0.f, 0.f, 0.f, 0.f);
            if (row < M) v = *(const float4*)(X + (size_t)row * K + kq * 4);
            __half2 h01 = __float22half2_rn(make_float2(v.x, v.y));
            __half2 h23 = __float22half2_rn(make_float2(v.z, v.w));
            uint2 u = make_uint2(*reinterpret_cast<unsigned*>(&h01),
                                 *reinterpret_cast<unsigned*>(&h23));
            *(uint2*)&Ah[r * LDA + kq * 4] = u;
        }
    } else {
#pragma unroll
        for (int j = 0; j < 4; ++j) {
            int lin = tid + j * 256;
            int r = lin >> 4, kq = lin & 15;
            int row = row0 + r;
            uint4 u = make_uint4(0, 0, 0, 0);
            if (row < M) u = *(const uint4*)(X + (size_t)row * K + kq * 8);
            *(uint4*)&Ah[r * LDA + kq * 8] = u;
        }
    }
    __syncthreads();

    int w = tid >> 6, l = tid & 63;
    int lr = l & 15, kg = l >> 4;
    f32x4 acc[NT];
#pragma unroll
    for (int nt = 0; nt < NT; ++nt) acc[nt] = (f32x4){0.f, 0.f, 0.f, 0.f};

    const _Float16* arow = &Ah[(w * 16 + lr) * LDA + kg * 8];
#pragma unroll
    for (int ks = 0; ks < 4; ++ks) {
        half8 af = *(const half8*)(arow + ks * 32);
#pragma unroll
        for (int nt = 0; nt < NT; ++nt) {
            half8 bf = *(const half8*)(&Bh[(nt * 16 + lr) * LDA + ks * 32 + kg * 8]);
            acc[nt] = __builtin_amdgcn_mfma_f32_16x16x32_f16(af, bf, acc[nt], 0, 0, 0);
        }
    }

#pragma unroll
    for (int j = 0; j < 4; ++j) {
        int grow = row0 + w * 16 + kg * 4 + j;
        if (grow < M) {
            float sc = dis[grow];
#pragma unroll
            for (int nt = 0; nt < NT; ++nt)
                Y[(size_t)grow * TN + nt * 16 + lr] = __float2half_rn(sc * acc[nt][j]);
        }
    }
}

// out[v] = dv*( sum_{e} Hs[src] + Hs[v] ) + b  (Hs pre-scaled by dis), opt relu.
// 16 lanes/node (4 streams/wave); single 8-edge batch buffer; tail gathers
// dummy zero row N. No launch_bounds waves-cap (R8: cap forced spill).
template<int C, bool RELU, typename TOUT>
__global__ __launch_bounds__(256) void agg_kernel(const __half* __restrict__ Hs,
                                                  const int* __restrict__ off,
                                                  const int* __restrict__ src,
                                                  const float* __restrict__ dis,
                                                  const float* __restrict__ bias,
                                                  TOUT* __restrict__ out, int N) {
    constexpr int HPL = C / 16;                  // halfs per lane: 8 or 4
    constexpr int NV = HPL / 2;                  // u32 words per row-slice
    using VT = std::conditional_t<HPL == 8, uint4, uint2>;
    int node = blockIdx.x * 16 + (threadIdx.x >> 4);
    if (node >= N) return;
    int lane = threadIdx.x & 15;
    const __half* hbase = Hs + lane * HPL;
    float dv = dis[node];
    float acc[HPL];
    {   // self term
        VT sv = *(const VT*)(hbase + (size_t)node * C);
        const unsigned int* u = reinterpret_cast<const unsigned int*>(&sv);
#pragma unroll
        for (int q = 0; q < NV; ++q) {
            float2 f = __half22float2(*reinterpret_cast<const __half2*>(&u[q]));
            acc[2 * q] = f.x;
            acc[2 * q + 1] = f.y;
        }
    }
    int e0 = off[node], e1 = off[node + 1];
    for (int e = e0; e < e1; e += 8) {
        int s[8];
#pragma unroll
        for (int k = 0; k < 8; ++k) {
            int idx = e + k;
            s[k] = (idx < e1) ? src[idx] : N;    // row N is all zeros
        }
        VT v[8];
#pragma unroll
        for (int k = 0; k < 8; ++k)
            v[k] = *(const VT*)(hbase + (size_t)s[k] * C);
#pragma unroll
        for (int k = 0; k < 8; ++k) {
            const unsigned int* u = reinterpret_cast<const unsigned int*>(&v[k]);
#pragma unroll
            for (int q = 0; q < NV; ++q) {
                float2 f = __half22float2(*reinterpret_cast<const __half2*>(&u[q]));
                acc[2 * q] += f.x;
                acc[2 * q + 1] += f.y;
            }
        }
    }
    float r[HPL];
#pragma unroll
    for (int f = 0; f < HPL; ++f) {
        r[f] = fmaf(dv, acc[f], bias[lane * HPL + f]);
        if (RELU) r[f] = fmaxf(r[f], 0.0f);
    }
    if constexpr (std::is_same<TOUT, __half>::value) {
        __half2 hv[NV];
#pragma unroll
        for (int q = 0; q < NV; ++q)
            hv[q] = __float22half2_rn(make_float2(r[2 * q], r[2 * q + 1]));
        *(VT*)(out + (size_t)node * C + lane * HPL) = *reinterpret_cast<VT*>(&hv[0]);
    } else {
        if constexpr (HPL == 8) {
            *(float4*)(out + (size_t)node * C + lane * 8) =
                make_float4(r[0], r[1], r[2], r[3]);
            *(float4*)(out + (size_t)node * C + lane * 8 + 4) =
                make_float4(r[4], r[5], r[6], r[7]);
        } else {
            *(float4*)(out + (size_t)node * C + lane * 4) =
                make_float4(r[0], r[1], r[2], r[3]);
        }
    }
}

extern "C" void kernel_launch(void* const* d_in, const int* in_sizes, int n_in,
                              void* d_out, int out_size, void* d_ws, size_t ws_size,
                              hipStream_t stream) {
    const float* x  = (const float*)d_in[0];
    const int*   ei = (const int*)d_in[1];
    const float* W1 = (const float*)d_in[2];
    const float* b1 = (const float*)d_in[3];
    const float* W2 = (const float*)d_in[4];
    const float* b2 = (const float*)d_in[5];
    float* out = (float*)d_out;

    int N = in_sizes[0] / 128;
    int E = in_sizes[1] / 2;
    const int* row = ei;        // edge_index[0] = sources
    const int* col = ei + E;    // edge_index[1] = targets
    int NB = (N + BNODES - 1) >> BSH;

    char* ws = (char*)d_ws;
    size_t o = 0;
    auto alloc = [&](size_t bytes) -> void* {
        void* p = ws + o;
        o = (o + bytes + 255) & ~(size_t)255;
        return p;
    };
    int*      bhist = (int*)alloc((size_t)(NB + 1) * 4);
    int*      bbase = (int*)alloc((size_t)(NB + 1) * 4);
    int*      bcur  = (int*)alloc((size_t)NB * 4);
    int*      off   = (int*)alloc((size_t)(N + 1) * 4);
    float*    dis   = (float*)alloc((size_t)N * 4);
    int*      csr   = (int*)alloc((size_t)E * 4);
    _Float16* w1t   = (_Float16*)alloc(128 * 128 * 2);
    _Float16* w2t   = (_Float16*)alloc(64 * 128 * 2);
    __half*   xw    = (__half*)alloc(((size_t)N * 128 + 128) * 2); // +dummy row N
    __half*   h     = (__half*)alloc(((size_t)N * 128 + 128) * 2); // +dummy row N
    int2*     pairs = (int2*)alloc((size_t)E * 8);                 // dead after place
    __half*   hw2   = xw;        // alias: dis*(h@W2), 64 cols (+dummy row N)

    zero_kernel<<<1, 256, 0, stream>>>(bhist, NB);
    wtrans_kernel<128><<<64, 256, 0, stream>>>(W1, w1t);
    wtrans_kernel<64><<<32, 256, 0, stream>>>(W2, w2t);
    hist_kernel<<<1024, 256, 0, stream>>>(col, bhist, E, NB);
    bbase_scan_kernel<<<1, 256, 0, stream>>>(bhist, bbase, bcur, NB);
    bucket_scatter_kernel<<<(E + CHUNK - 1) / CHUNK, 256, 0, stream>>>(row, col, bcur,
                                                                       pairs, E, NB);
    place_kernel<<<NB, 256, 0, stream>>>(pairs, bbase, off, dis, csr, N, NB);

    gemm_kernel<128, float><<<(N + 63) / 64, 256, 0, stream>>>(x, w1t, dis, xw, N);
    zero_halfs_kernel<<<1, 256, 0, stream>>>(xw + (size_t)N * 128, 128);  // agg1 dummy
    agg_kernel<128, true, __half><<<(N + 15) / 16, 256, 0, stream>>>(xw, off, csr, dis,
                                                                     b1, h, N);
    gemm_kernel<64, __half><<<(N + 63) / 64, 256, 0, stream>>>(h, w2t, dis, hw2, N);
    // hw2 aliases xw: its dummy row N ([N*64, N*64+64) halves) holds stale xw
    // data — safe to zero only AFTER agg1 consumed xw.
    zero_halfs_kernel<<<1, 256, 0, stream>>>(hw2 + (size_t)N * 64, 64);   // agg2 dummy
    agg_kernel<64, false, float><<<(N + 15) / 16, 256, 0, stream>>>(hw2, off, csr, dis,
                                                                    b2, out, N);
}